// Round 4
// baseline (2327.702 us; speedup 1.0000x reference)
//
#include <hip/hip_runtime.h>
#include <hip/hip_bf16.h>
#include <cmath>

typedef __bf16 bf16_t;
typedef __bf16 bf16x8 __attribute__((ext_vector_type(8)));
typedef __bf16 bf16x4 __attribute__((ext_vector_type(4)));
typedef float f32x4 __attribute__((ext_vector_type(4)));

#define LATENT 1024
#define HEADS 16
#define HD 64
#define TX 4096
#define TXF 256
#define SCALE_ATTN 0.125f

static __device__ __forceinline__ float b2f(bf16_t b) { return (float)b; }
static __device__ __forceinline__ bf16_t f2b(float f) { return (bf16_t)f; }

// async global->LDS, 16B per lane; LDS dest = wave-uniform base + lane*16
static __device__ __forceinline__ void glds16(const bf16_t* g, bf16_t* l) {
    __builtin_amdgcn_global_load_lds(
        (const __attribute__((address_space(1))) void*)g,
        (__attribute__((address_space(3))) void*)l, 16, 0, 0);
}

#define MFMA16(a, b, c) __builtin_amdgcn_mfma_f32_16x16x32_bf16(a, b, c, 0, 0, 0)

// ---------------- f32 -> bf16 convert (vectorized, grid-stride) ----------
__global__ __launch_bounds__(256) void cvt_k(const float* __restrict__ in,
                                             bf16_t* __restrict__ out, long n4) {
    long i = (long)blockIdx.x * 256 + threadIdx.x;
    long stride = (long)gridDim.x * 256;
    for (; i < n4; i += stride) {
        float4 v = ((const float4*)in)[i];
        bf16x4 o;
        o[0] = f2b(v.x); o[1] = f2b(v.y); o[2] = f2b(v.z); o[3] = f2b(v.w);
        *(bf16x4*)&out[i * 4] = o;
    }
}

// ------------- transpose+convert: in f32 [R][C] -> out bf16 [C][R] -------
__global__ __launch_bounds__(256) void tr_k(const float* __restrict__ in,
                                            bf16_t* __restrict__ out,
                                            int R, int C) {
    __shared__ float t[32][33];
    int bx = blockIdx.x, by = blockIdx.y;
    int x = threadIdx.x & 31, y0 = threadIdx.x >> 5;  // 32 x 8
    for (int i = 0; i < 32; i += 8)
        t[y0 + i][x] = in[(long)(by * 32 + y0 + i) * C + bx * 32 + x];
    __syncthreads();
    for (int i = 0; i < 32; i += 8)
        out[(long)(bx * 32 + y0 + i) * R + by * 32 + x] = f2b(t[x][y0 + i]);
}

// ---------------- GEMM 128x128 (m97 structure) — small shapes only -------
// C[M,N] = A[M,K] @ Bt[N,K]^T + bias(f32)
template <int EPI>
__global__ __launch_bounds__(256, 2) void gemm_k(
    const bf16_t* __restrict__ A, const bf16_t* __restrict__ Bt,
    const float* __restrict__ bias, void* __restrict__ C,
    const bf16_t* __restrict__ resb16, const float* __restrict__ resf32,
    int M, int N, int K) {
    __shared__ __align__(16) bf16_t As[128 * 64];
    __shared__ __align__(16) bf16_t Bs[128 * 64];
    int tid = threadIdx.x;
    int lane = tid & 63, wid = tid >> 6;
    int quad = lane >> 4, l16 = lane & 15;
    int wm = wid >> 1, wn = wid & 1;
    int srow0 = wid * 8 + (lane >> 3);
    int schunk = (lane & 7) ^ (lane >> 3);

    f32x4 acc[4][4] = {};
    long bm = blockIdx.x, bn = blockIdx.y;
    const bf16_t* Ab = A + (bm * 128 + srow0) * (long)K + schunk * 8;
    const bf16_t* Bb = Bt + (bn * 128 + srow0) * (long)K + schunk * 8;
    bf16_t* AsD = As + wid * 512;
    bf16_t* BsD = Bs + wid * 512;

    for (int k0 = 0; k0 < K; k0 += 64) {
        __syncthreads();
#pragma unroll
        for (int t = 0; t < 4; t++) {
            glds16(Ab + k0 + (long)t * 32 * K, AsD + t * 2048);
            glds16(Bb + k0 + (long)t * 32 * K, BsD + t * 2048);
        }
        __syncthreads();
#pragma unroll
        for (int s = 0; s < 2; s++) {
            bf16x8 af[4], bfr[4];
#pragma unroll
            for (int mi = 0; mi < 4; mi++) {
                int r = wm * 64 + mi * 16 + l16;
                af[mi] = *(const bf16x8*)&As[r * 64 + (((s * 4 + quad) ^ (r & 7)) * 8)];
            }
#pragma unroll
            for (int ni = 0; ni < 4; ni++) {
                int r = wn * 64 + ni * 16 + l16;
                bfr[ni] = *(const bf16x8*)&Bs[r * 64 + (((s * 4 + quad) ^ (r & 7)) * 8)];
            }
#pragma unroll
            for (int mi = 0; mi < 4; mi++)
#pragma unroll
                for (int ni = 0; ni < 4; ni++)
                    acc[mi][ni] = MFMA16(af[mi], bfr[ni], acc[mi][ni]);
        }
    }

    int colb = (int)bn * 128 + wn * 64;
    float bvv[4];
#pragma unroll
    for (int ni = 0; ni < 4; ni++) bvv[ni] = bias[colb + ni * 16 + l16];
#pragma unroll
    for (int mi = 0; mi < 4; mi++) {
        long grow = bm * 128 + wm * 64 + mi * 16 + quad * 4;
#pragma unroll
        for (int r = 0; r < 4; r++) {
            long ro = (grow + r) * (long)N;
#pragma unroll
            for (int ni = 0; ni < 4; ni++) {
                long idx = ro + colb + ni * 16 + l16;
                float v = acc[mi][ni][r] + bvv[ni];
                if (EPI == 0) {
                    ((bf16_t*)C)[idx] = f2b(v);
                } else if (EPI == 2) {
                    ((bf16_t*)C)[idx] =
                        f2b(0.5f * v * (1.0f + erff(v * 0.70710678118f)));
                } else {
                    ((float*)C)[idx] = v + b2f(resb16[idx]) + resf32[idx];
                }
            }
        }
    }
}

// ------------- GEMM 256x256, BK=64, 8 waves, alias-proof double buffer ---
// C[M,N] = A[M,K] @ Bt[N,K]^T + bias. M%256==0, N%256==0.
// FOUR distinct LDS arrays (As0/As1/Bs0/Bs1): waitcnt pass can prove
// ds_reads from buffer X never alias outstanding global_load_lds DMA into
// buffer Y -> no implicit vmcnt(0) drain inside the tile body. Loop is
// manually unrolled x2 so every LDS base is a compile-time-known array.
// Register discipline (spill fix vs r3): ONE af[4][2] reused across both
// M-halves + one bq[4][2] = 64 fragment VGPRs; peak live ~192 < 256 cap.
// Per tile: stage(t+1 -> other pair) issued FIRST, then 16 ds_read,
// 32 MFMA (half0), 8 ds_read (half1, WAR reuse), 32 MFMA, vmcnt(0), barrier.
template <int EPI>
__global__ __launch_bounds__(512, 2) void gemm256_k(
    const bf16_t* __restrict__ A, const bf16_t* __restrict__ Bt,
    const float* __restrict__ bias, void* __restrict__ C,
    const bf16_t* __restrict__ resb16, const float* __restrict__ resf32,
    int M, int N, int K) {
    __shared__ __align__(16) bf16_t As0[16384];
    __shared__ __align__(16) bf16_t As1[16384];
    __shared__ __align__(16) bf16_t Bs0[16384];
    __shared__ __align__(16) bf16_t Bs1[16384];
    int tid = threadIdx.x;
    int lane = tid & 63, wid = tid >> 6;      // 8 waves
    int quad = lane >> 4, l16 = lane & 15;
    int wm = wid >> 2, wn = wid & 3;          // 2 x 4 wave grid
    long bm = blockIdx.x, bn = blockIdx.y;
    int NT = K >> 6;

    // staging: round r covers rows [r*64, r*64+64); wave wid handles 8 rows.
    // source chunk pre-swizzled so linear LDS write == swizzled layout.
    int srow = wid * 8 + (lane >> 3);
    int schunk = ((lane & 7) ^ (lane >> 3)) * 8;
    const bf16_t* Asrc = A + (bm * 256 + srow) * (long)K + schunk;
    const bf16_t* Bsrc = Bt + (bn * 256 + srow) * (long)K + schunk;

    auto stage = [&](bf16_t* Ad, bf16_t* Bd, int t) {
#pragma unroll
        for (int r = 0; r < 4; ++r)
            glds16(Asrc + ((long)t * 64 + (long)r * 64 * K),
                   Ad + r * 4096 + wid * 512);
#pragma unroll
        for (int r = 0; r < 4; ++r)
            glds16(Bsrc + ((long)t * 64 + (long)r * 64 * K),
                   Bd + r * 4096 + wid * 512);
    };

    f32x4 acc[8][4] = {};
    bf16x8 af[4][2], bq[4][2];

    auto loadB = [&](const bf16_t* BL) {
#pragma unroll
        for (int ni = 0; ni < 4; ++ni) {
            int r = wn * 64 + ni * 16 + l16;
            bq[ni][0] = *(const bf16x8*)&BL[r * 64 + ((quad ^ (r & 7)) * 8)];
            bq[ni][1] = *(const bf16x8*)&BL[r * 64 + (((4 + quad) ^ (r & 7)) * 8)];
        }
    };
    auto loadA = [&](const bf16_t* AL, int half) {
#pragma unroll
        for (int mi = 0; mi < 4; ++mi) {
            int r = wm * 128 + half * 64 + mi * 16 + l16;
            af[mi][0] = *(const bf16x8*)&AL[r * 64 + ((quad ^ (r & 7)) * 8)];
            af[mi][1] = *(const bf16x8*)&AL[r * 64 + (((4 + quad) ^ (r & 7)) * 8)];
        }
    };
    auto mfmaHalf = [&](int half) {
        __builtin_amdgcn_s_setprio(1);
#pragma unroll
        for (int mi = 0; mi < 4; ++mi)
#pragma unroll
            for (int ni = 0; ni < 4; ++ni) {
                acc[half * 4 + mi][ni] =
                    MFMA16(af[mi][0], bq[ni][0], acc[half * 4 + mi][ni]);
                acc[half * 4 + mi][ni] =
                    MFMA16(af[mi][1], bq[ni][1], acc[half * 4 + mi][ni]);
            }
        __builtin_amdgcn_s_setprio(0);
    };

    // prologue: tile 0 -> buf0
    stage(As0, Bs0, 0);
    asm volatile("s_waitcnt vmcnt(0)" ::: "memory");
    __builtin_amdgcn_s_barrier();

    int t = 0;
    while (true) {
        // ---- tile t from buf0; stage t+1 -> buf1 (issued before compute)
        if (t + 1 < NT) stage(As1, Bs1, t + 1);
        loadB(Bs0);
        loadA(As0, 0);
        mfmaHalf(0);
        loadA(As0, 1);
        mfmaHalf(1);
        asm volatile("s_waitcnt vmcnt(0)" ::: "memory");
        __builtin_amdgcn_s_barrier();
        if (++t >= NT) break;
        // ---- tile t from buf1; stage t+1 -> buf0
        if (t + 1 < NT) stage(As0, Bs0, t + 1);
        loadB(Bs1);
        loadA(As1, 0);
        mfmaHalf(0);
        loadA(As1, 1);
        mfmaHalf(1);
        asm volatile("s_waitcnt vmcnt(0)" ::: "memory");
        __builtin_amdgcn_s_barrier();
        if (++t >= NT) break;
    }

    // epilogue — C/D: col = lane&15, row = quad*4 + reg
    int colb = (int)bn * 256 + wn * 64;
    float bvv[4];
#pragma unroll
    for (int ni = 0; ni < 4; ++ni) bvv[ni] = bias[colb + ni * 16 + l16];
#pragma unroll
    for (int mi = 0; mi < 8; ++mi) {
        long grow = bm * 256 + wm * 128 + mi * 16 + quad * 4;
#pragma unroll
        for (int r = 0; r < 4; ++r) {
            long ro = (grow + r) * (long)N;
#pragma unroll
            for (int ni = 0; ni < 4; ++ni) {
                long idx = ro + colb + ni * 16 + l16;
                float v = acc[mi][ni][r] + bvv[ni];
                if (EPI == 0) {
                    ((bf16_t*)C)[idx] = f2b(v);
                } else if (EPI == 2) {
                    ((bf16_t*)C)[idx] =
                        f2b(0.5f * v * (1.0f + erff(v * 0.70710678118f)));
                } else {
                    ((float*)C)[idx] = v + b2f(resb16[idx]) + resf32[idx];
                }
            }
        }
    }
}

// ---------------- fused attention (all-bf16 internal buffers) ------------
__global__ __launch_bounds__(256, 2) void attn_k(const bf16_t* __restrict__ Q,
                                                 const bf16_t* __restrict__ Kb,
                                                 const bf16_t* __restrict__ Vb,
                                                 bf16_t* __restrict__ Ob) {
    __shared__ __align__(16) bf16_t SM[32768];
    bf16_t* Ks = SM;
    bf16_t* Vt = SM + 16384;
    int tid = threadIdx.x;
    int lane = tid & 63, w = tid >> 6;
    int quad = lane >> 4, l16 = lane & 15;
    int qt = blockIdx.x & 63;
    int bh = blockIdx.x >> 6;
    int b = bh >> 4, h = bh & 15;

    {  // stage K (natural, swizzled) + V (transposed, swizzled); row = tid
        const uint4* ks = (const uint4*)(Kb + ((long)(b * TXF + tid) * LATENT + h * HD));
#pragma unroll
        for (int cc = 0; cc < 8; cc++)
            *(uint4*)&Ks[tid * 64 + ((cc ^ (tid & 7)) * 8)] = ks[cc];
        const uint4* vs = (const uint4*)(Vb + ((long)(b * TXF + tid) * LATENT + h * HD));
#pragma unroll
        for (int cc = 0; cc < 8; cc++) {
            uint4 v = vs[cc];
            const bf16_t* e = (const bf16_t*)&v;
#pragma unroll
            for (int j = 0; j < 8; j++) {
                int d = cc * 8 + j;
                Vt[d * 256 + (((tid >> 3) ^ (d & 7)) * 8) + (tid & 7)] = e[j];
            }
        }
    }
    long qrow = (long)(b * TX + qt * 64 + w * 16 + l16) * LATENT + h * HD;
    bf16x8 aq0 = *(const bf16x8*)(Q + qrow + quad * 8);
    bf16x8 aq1 = *(const bf16x8*)(Q + qrow + 32 + quad * 8);
    __syncthreads();

    f32x4 sacc[16] = {};
#pragma unroll
    for (int ni = 0; ni < 16; ni++) {
        int kr = ni * 16 + l16;
        bf16x8 b0 = *(const bf16x8*)&Ks[kr * 64 + ((quad ^ (kr & 7)) * 8)];
        bf16x8 b1 = *(const bf16x8*)&Ks[kr * 64 + (((4 + quad) ^ (kr & 7)) * 8)];
        sacc[ni] = MFMA16(aq0, b0, sacc[ni]);
        sacc[ni] = MFMA16(aq1, b1, sacc[ni]);
    }
#pragma unroll
    for (int r = 0; r < 4; r++) {
        float m = -3e38f;
#pragma unroll
        for (int ni = 0; ni < 16; ni++) m = fmaxf(m, sacc[ni][r]);
#pragma unroll
        for (int off = 1; off < 16; off <<= 1) m = fmaxf(m, __shfl_xor(m, off, 64));
        float s = 0.f;
#pragma unroll
        for (int ni = 0; ni < 16; ni++) {
            float p = __expf((sacc[ni][r] - m) * SCALE_ATTN);
            sacc[ni][r] = p;
            s += p;
        }
#pragma unroll
        for (int off = 1; off < 16; off <<= 1) s += __shfl_xor(s, off, 64);
        float inv = 1.0f / s;
#pragma unroll
        for (int ni = 0; ni < 16; ni++) sacc[ni][r] *= inv;
    }
    __syncthreads();

    bf16_t* Ps = SM;
#pragma unroll
    for (int r = 0; r < 4; r++) {
        int row = w * 16 + quad * 4 + r;
#pragma unroll
        for (int ni = 0; ni < 16; ni++) {
            int col = ni * 16 + l16;
            Ps[row * 256 + (((col >> 3) ^ (row & 7)) * 8) + (col & 7)] =
                f2b(sacc[ni][r]);
        }
    }
    __syncthreads();

    f32x4 oacc[4] = {};
#pragma unroll
    for (int s = 0; s < 8; s++) {
        int prow = w * 16 + l16;
        bf16x8 ap = *(const bf16x8*)&Ps[prow * 256 + (((s * 4 + quad) ^ (prow & 7)) * 8)];
#pragma unroll
        for (int ni = 0; ni < 4; ni++) {
            int vr = ni * 16 + l16;
            bf16x8 bv = *(const bf16x8*)&Vt[vr * 256 + (((s * 4 + quad) ^ (vr & 7)) * 8)];
            oacc[ni] = MFMA16(ap, bv, oacc[ni]);
        }
    }
#pragma unroll
    for (int r = 0; r < 4; r++) {
        long orow = (long)(b * TX + qt * 64 + w * 16 + quad * 4 + r) * LATENT + h * HD;
#pragma unroll
        for (int ni = 0; ni < 4; ni++)
            Ob[orow + ni * 16 + l16] = f2b(oacc[ni][r]);
    }
}

// ------- LayerNorm: bf16 in, f32 gamma/beta (raw inputs), bf16 out -------
__global__ __launch_bounds__(256) void ln_k(const bf16_t* __restrict__ O,
                                            const float* __restrict__ g,
                                            const float* __restrict__ bb,
                                            bf16_t* __restrict__ H) {
    long row = blockIdx.x;
    int c = threadIdx.x * 4;
    bf16x4 v = *(const bf16x4*)(O + row * LATENT + c);
    float vv[4] = {b2f(v[0]), b2f(v[1]), b2f(v[2]), b2f(v[3])};
    float s = vv[0] + vv[1] + vv[2] + vv[3];
    float s2 = vv[0] * vv[0] + vv[1] * vv[1] + vv[2] * vv[2] + vv[3] * vv[3];
#pragma unroll
    for (int off = 1; off < 64; off <<= 1) {
        s += __shfl_xor(s, off, 64);
        s2 += __shfl_xor(s2, off, 64);
    }
    __shared__ float red[8];
    int lane = threadIdx.x & 63, w = threadIdx.x >> 6;
    if (lane == 0) { red[w] = s; red[w + 4] = s2; }
    __syncthreads();
    s = red[0] + red[1] + red[2] + red[3];
    s2 = red[4] + red[5] + red[6] + red[7];
    float mu = s * (1.0f / 1024.0f);
    float var = s2 * (1.0f / 1024.0f) - mu * mu;
    float rstd = rsqrtf(var + 1e-5f);
    bf16_t* out = H + row * LATENT + c;
#pragma unroll
    for (int j = 0; j < 4; j++)
        out[j] = f2b((vv[j] - mu) * rstd * g[c + j] + bb[c + j]);
}

// ---------------- launch ----------------
extern "C" void kernel_launch(void* const* d_in, const int* in_sizes, int n_in,
                              void* d_out, int out_size, void* d_ws,
                              size_t ws_size, hipStream_t stream) {
    const float* x = (const float*)d_in[0];
    const float* xf = (const float*)d_in[1];
    const float* Wq = (const float*)d_in[2];
    const float* bq = (const float*)d_in[3];
    const float* Wk = (const float*)d_in[4];
    const float* bk = (const float*)d_in[5];
    const float* Wv = (const float*)d_in[6];
    const float* bv = (const float*)d_in[7];
    const float* Wo = (const float*)d_in[8];
    const float* bo = (const float*)d_in[9];
    const float* lng = (const float*)d_in[10];
    const float* lnb = (const float*)d_in[11];
    const float* W1 = (const float*)d_in[12];
    const float* b1 = (const float*)d_in[13];
    const float* W2 = (const float*)d_in[14];
    const float* b2 = (const float*)d_in[15];

    char* ws = (char*)d_ws;
    size_t off = 0;
    auto alloc = [&](size_t bytes) {
        void* p = ws + off;
        off += (bytes + 255) & ~(size_t)255;
        return p;
    };
    bf16_t* WqT = (bf16_t*)alloc((size_t)1024 * 1024 * 2);
    bf16_t* WkT = (bf16_t*)alloc((size_t)1024 * 768 * 2);
    bf16_t* WvT = (bf16_t*)alloc((size_t)1024 * 768 * 2);
    bf16_t* WoT = (bf16_t*)alloc((size_t)1024 * 1024 * 2);
    bf16_t* W1T = (bf16_t*)alloc((size_t)4096 * 1024 * 2);
    bf16_t* W2T = (bf16_t*)alloc((size_t)1024 * 4096 * 2);
    bf16_t* Obuf = (bf16_t*)alloc((size_t)16384 * 1024 * 2);
    bf16_t* Hbuf = (bf16_t*)alloc((size_t)16384 * 1024 * 2);
    size_t transient0 = off;
    bf16_t* xc = (bf16_t*)alloc((size_t)16384 * 1024 * 2);
    bf16_t* xfc = (bf16_t*)alloc((size_t)1024 * 768 * 2);
    bf16_t* Qbuf = (bf16_t*)alloc((size_t)16384 * 1024 * 2);
    bf16_t* Kbuf = (bf16_t*)alloc((size_t)1024 * 1024 * 2);
    bf16_t* Vbuf = (bf16_t*)alloc((size_t)1024 * 1024 * 2);
    bf16_t* Abuf = (bf16_t*)alloc((size_t)16384 * 1024 * 2);
    bf16_t* H1 = (bf16_t*)(ws + transient0);

    dim3 blk(256), blk5(512);
    cvt_k<<<dim3(4096), blk, 0, stream>>>(x, xc, (long)16384 * 1024 / 4);
    cvt_k<<<dim3(768), blk, 0, stream>>>(xf, xfc, (long)1024 * 768 / 4);
    tr_k<<<dim3(32, 32), blk, 0, stream>>>(Wq, WqT, 1024, 1024);
    tr_k<<<dim3(32, 24), blk, 0, stream>>>(Wk, WkT, 768, 1024);
    tr_k<<<dim3(32, 24), blk, 0, stream>>>(Wv, WvT, 768, 1024);
    tr_k<<<dim3(32, 32), blk, 0, stream>>>(Wo, WoT, 1024, 1024);
    tr_k<<<dim3(128, 32), blk, 0, stream>>>(W1, W1T, 1024, 4096);
    tr_k<<<dim3(32, 128), blk, 0, stream>>>(W2, W2T, 4096, 1024);

    // projections
    gemm256_k<0><<<dim3(64, 4), blk5, 0, stream>>>(xc, WqT, bq, Qbuf, nullptr, nullptr, 16384, 1024, 1024);
    gemm_k<0><<<dim3(8, 8), blk, 0, stream>>>(xfc, WkT, bk, Kbuf, nullptr, nullptr, 1024, 1024, 768);
    gemm_k<0><<<dim3(8, 8), blk, 0, stream>>>(xfc, WvT, bv, Vbuf, nullptr, nullptr, 1024, 1024, 768);
    // attention
    attn_k<<<dim3(4096), blk, 0, stream>>>(Qbuf, Kbuf, Vbuf, Abuf);
    // output projection
    gemm256_k<0><<<dim3(64, 4), blk5, 0, stream>>>(Abuf, WoT, bo, Obuf, nullptr, nullptr, 16384, 1024, 1024);
    // layernorm
    ln_k<<<dim3(16384), blk, 0, stream>>>(Obuf, lng, lnb, Hbuf);
    // FFN
    gemm256_k<2><<<dim3(64, 16), blk5, 0, stream>>>(Hbuf, W1T, b1, H1, nullptr, nullptr, 16384, 4096, 1024);
    gemm256_k<3><<<dim3(64, 4), blk5, 0, stream>>>(H1, W2T, b2, d_out, Obuf, x, 16384, 1024, 4096);
}

// Round 5
// 732.796 us; speedup vs baseline: 3.1765x; 3.1765x over previous
//
#include <hip/hip_runtime.h>
#include <hip/hip_bf16.h>
#include <cmath>

typedef __bf16 bf16_t;
typedef __bf16 bf16x8 __attribute__((ext_vector_type(8)));
typedef __bf16 bf16x4 __attribute__((ext_vector_type(4)));
typedef float f32x4 __attribute__((ext_vector_type(4)));

#define LATENT 1024
#define HEADS 16
#define HD 64
#define TX 4096
#define TXF 256
#define SCALE_ATTN 0.125f

static __device__ __forceinline__ float b2f(bf16_t b) { return (float)b; }
static __device__ __forceinline__ bf16_t f2b(float f) { return (bf16_t)f; }

// async global->LDS, 16B per lane; LDS dest = wave-uniform base + lane*16
static __device__ __forceinline__ void glds16(const bf16_t* g, bf16_t* l) {
    __builtin_amdgcn_global_load_lds(
        (const __attribute__((address_space(1))) void*)g,
        (__attribute__((address_space(3))) void*)l, 16, 0, 0);
}

#define MFMA16(a, b, c) __builtin_amdgcn_mfma_f32_16x16x32_bf16(a, b, c, 0, 0, 0)

// ---------------- f32 -> bf16 convert (vectorized, grid-stride) ----------
__global__ __launch_bounds__(256) void cvt_k(const float* __restrict__ in,
                                             bf16_t* __restrict__ out, long n4) {
    long i = (long)blockIdx.x * 256 + threadIdx.x;
    long stride = (long)gridDim.x * 256;
    for (; i < n4; i += stride) {
        float4 v = ((const float4*)in)[i];
        bf16x4 o;
        o[0] = f2b(v.x); o[1] = f2b(v.y); o[2] = f2b(v.z); o[3] = f2b(v.w);
        *(bf16x4*)&out[i * 4] = o;
    }
}

// ------ merged transpose+convert for all 6 weights: f32 [R][C] -> bf16 [C][R]
// tile ranges (32x32 tiles, x-fastest like tr_k's grid (C/32, R/32)):
//   Wq 32x32=1024 | Wk 32x24=768 | Wv 768 | Wo 1024 | W1 128x32=4096 | W2 32x128=4096
__global__ __launch_bounds__(256) void tr6_k(
    const float* __restrict__ s0, bf16_t* __restrict__ d0,
    const float* __restrict__ s1, bf16_t* __restrict__ d1,
    const float* __restrict__ s2, bf16_t* __restrict__ d2,
    const float* __restrict__ s3, bf16_t* __restrict__ d3,
    const float* __restrict__ s4, bf16_t* __restrict__ d4,
    const float* __restrict__ s5, bf16_t* __restrict__ d5) {
    int id = blockIdx.x;
    const float* src; bf16_t* dst; int R, C, bx, by;
    if (id < 1024)      { src = s0; dst = d0; R = 1024; C = 1024; bx = id & 31;  by = id >> 5; }
    else if (id < 1792) { id -= 1024; src = s1; dst = d1; R = 768;  C = 1024; bx = id & 31;  by = id >> 5; }
    else if (id < 2560) { id -= 1792; src = s2; dst = d2; R = 768;  C = 1024; bx = id & 31;  by = id >> 5; }
    else if (id < 3584) { id -= 2560; src = s3; dst = d3; R = 1024; C = 1024; bx = id & 31;  by = id >> 5; }
    else if (id < 7680) { id -= 3584; src = s4; dst = d4; R = 1024; C = 4096; bx = id & 127; by = id >> 7; }
    else                { id -= 7680; src = s5; dst = d5; R = 4096; C = 1024; bx = id & 31;  by = id >> 5; }
    __shared__ float t[32][33];
    int x = threadIdx.x & 31, y0 = threadIdx.x >> 5;  // 32 x 8
    for (int i = 0; i < 32; i += 8)
        t[y0 + i][x] = src[(long)(by * 32 + y0 + i) * C + bx * 32 + x];
    __syncthreads();
    for (int i = 0; i < 32; i += 8)
        dst[(long)(bx * 32 + y0 + i) * R + by * 32 + x] = f2b(t[x][y0 + i]);
}

// ---------------- GEMM: C[M,N] = A[M,K] @ Bt[N,K]^T + bias(f32) ----------
// 128x128 tile, BK=64, m97 2-sync structure (verified 41% MfmaUtil, 64 VGPR).
// T1: bijective XCD-chunk swizzle of the linear block id (all launches use
// nwg % 8 == 0). EPI: 0 = bf16 store, 2 = exact-GELU -> bf16,
//      3 = + resb16(bf16) + resf32(f32) -> F32 store (final output)
template <int EPI>
__global__ __launch_bounds__(256, 2) void gemm_k(
    const bf16_t* __restrict__ A, const bf16_t* __restrict__ Bt,
    const float* __restrict__ bias, void* __restrict__ C,
    const bf16_t* __restrict__ resb16, const float* __restrict__ resf32,
    int M, int N, int K) {
    __shared__ __align__(16) bf16_t As[128 * 64];
    __shared__ __align__(16) bf16_t Bs[128 * 64];
    int tid = threadIdx.x;
    int lane = tid & 63, wid = tid >> 6;
    int quad = lane >> 4, l16 = lane & 15;
    int wm = wid >> 1, wn = wid & 1;
    int srow0 = wid * 8 + (lane >> 3);
    int schunk = (lane & 7) ^ (lane >> 3);

    // XCD-aware bijective remap: hardware round-robins linear id over 8 XCDs;
    // give XCD j the contiguous logical chunk [j*cpx, (j+1)*cpx).
    int nwg = gridDim.x * gridDim.y;
    int wgid = blockIdx.y * gridDim.x + blockIdx.x;
    int cpx = nwg >> 3;
    int swz = (wgid & 7) * cpx + (wgid >> 3);
    long bm = swz % gridDim.x;
    long bn = swz / gridDim.x;

    f32x4 acc[4][4] = {};
    const bf16_t* Ab = A + (bm * 128 + srow0) * (long)K + schunk * 8;
    const bf16_t* Bb = Bt + (bn * 128 + srow0) * (long)K + schunk * 8;
    bf16_t* AsD = As + wid * 512;  // +t*2048; HW adds lane*16B (=lane*8 elems)
    bf16_t* BsD = Bs + wid * 512;

    for (int k0 = 0; k0 < K; k0 += 64) {
        __syncthreads();  // previous compute done reading LDS
#pragma unroll
        for (int t = 0; t < 4; t++) {
            glds16(Ab + k0 + (long)t * 32 * K, AsD + t * 2048);
            glds16(Bb + k0 + (long)t * 32 * K, BsD + t * 2048);
        }
        __syncthreads();  // drains vmcnt -> LDS ready
#pragma unroll
        for (int s = 0; s < 2; s++) {
            bf16x8 af[4], bfr[4];
#pragma unroll
            for (int mi = 0; mi < 4; mi++) {
                int r = wm * 64 + mi * 16 + l16;
                af[mi] = *(const bf16x8*)&As[r * 64 + (((s * 4 + quad) ^ (r & 7)) * 8)];
            }
#pragma unroll
            for (int ni = 0; ni < 4; ni++) {
                int r = wn * 64 + ni * 16 + l16;
                bfr[ni] = *(const bf16x8*)&Bs[r * 64 + (((s * 4 + quad) ^ (r & 7)) * 8)];
            }
#pragma unroll
            for (int mi = 0; mi < 4; mi++)
#pragma unroll
                for (int ni = 0; ni < 4; ni++)
                    acc[mi][ni] = MFMA16(af[mi], bfr[ni], acc[mi][ni]);
        }
    }

    // C/D layout: col = lane&15, row = quad*4 + reg (verified m89/m91)
    int colb = (int)bn * 128 + wn * 64;
    float bvv[4];
#pragma unroll
    for (int ni = 0; ni < 4; ni++) bvv[ni] = bias[colb + ni * 16 + l16];
#pragma unroll
    for (int mi = 0; mi < 4; mi++) {
        long grow = bm * 128 + wm * 64 + mi * 16 + quad * 4;
#pragma unroll
        for (int r = 0; r < 4; r++) {
            long ro = (grow + r) * (long)N;
#pragma unroll
            for (int ni = 0; ni < 4; ni++) {
                long idx = ro + colb + ni * 16 + l16;
                float v = acc[mi][ni][r] + bvv[ni];
                if (EPI == 0) {
                    ((bf16_t*)C)[idx] = f2b(v);
                } else if (EPI == 2) {
                    ((bf16_t*)C)[idx] =
                        f2b(0.5f * v * (1.0f + erff(v * 0.70710678118f)));
                } else {
                    // final: ffn + attn_out(bf16) + x(f32), stored f32
                    ((float*)C)[idx] = v + b2f(resb16[idx]) + resf32[idx];
                }
            }
        }
    }
}

// ---------------- fused attention (all-bf16 internal buffers) ------------
// Q[16384,1024], K/V[1024,1024] laid out (b*T + t, h*64 + d).
// Block: 64 q-rows of one (b,h). LDS 64KB: Ks swizzled [256][64] (later
// aliased by Ps [64][256]); Vt transposed swizzled [64 d][256 kk].
__global__ __launch_bounds__(256, 2) void attn_k(const bf16_t* __restrict__ Q,
                                                 const bf16_t* __restrict__ Kb,
                                                 const bf16_t* __restrict__ Vb,
                                                 bf16_t* __restrict__ Ob) {
    __shared__ __align__(16) bf16_t SM[32768];
    bf16_t* Ks = SM;
    bf16_t* Vt = SM + 16384;
    int tid = threadIdx.x;
    int lane = tid & 63, w = tid >> 6;
    int quad = lane >> 4, l16 = lane & 15;
    int qt = blockIdx.x & 63;
    int bh = blockIdx.x >> 6;
    int b = bh >> 4, h = bh & 15;

    {  // stage K (natural, swizzled) + V (transposed, swizzled); row = tid
        const uint4* ks = (const uint4*)(Kb + ((long)(b * TXF + tid) * LATENT + h * HD));
#pragma unroll
        for (int cc = 0; cc < 8; cc++)
            *(uint4*)&Ks[tid * 64 + ((cc ^ (tid & 7)) * 8)] = ks[cc];
        const uint4* vs = (const uint4*)(Vb + ((long)(b * TXF + tid) * LATENT + h * HD));
#pragma unroll
        for (int cc = 0; cc < 8; cc++) {
            uint4 v = vs[cc];
            const bf16_t* e = (const bf16_t*)&v;
#pragma unroll
            for (int j = 0; j < 8; j++) {
                int d = cc * 8 + j;
                Vt[d * 256 + (((tid >> 3) ^ (d & 7)) * 8) + (tid & 7)] = e[j];
            }
        }
    }
    // Q A-fragments from global (read-once): A[m=lane&15][k=quad*8+j]
    long qrow = (long)(b * TX + qt * 64 + w * 16 + l16) * LATENT + h * HD;
    bf16x8 aq0 = *(const bf16x8*)(Q + qrow + quad * 8);
    bf16x8 aq1 = *(const bf16x8*)(Q + qrow + 32 + quad * 8);
    __syncthreads();

    // scores: wave w owns q-rows [w*16, w*16+16), all 256 cols
    f32x4 sacc[16] = {};
#pragma unroll
    for (int ni = 0; ni < 16; ni++) {
        int kr = ni * 16 + l16;
        bf16x8 b0 = *(const bf16x8*)&Ks[kr * 64 + ((quad ^ (kr & 7)) * 8)];
        bf16x8 b1 = *(const bf16x8*)&Ks[kr * 64 + (((4 + quad) ^ (kr & 7)) * 8)];
        sacc[ni] = MFMA16(aq0, b0, sacc[ni]);
        sacc[ni] = MFMA16(aq1, b1, sacc[ni]);
    }
    // softmax per row (row = quad*4 + r); 16-lane butterfly stays in quad
#pragma unroll
    for (int r = 0; r < 4; r++) {
        float m = -3e38f;
#pragma unroll
        for (int ni = 0; ni < 16; ni++) m = fmaxf(m, sacc[ni][r]);
#pragma unroll
        for (int off = 1; off < 16; off <<= 1) m = fmaxf(m, __shfl_xor(m, off, 64));
        float s = 0.f;
#pragma unroll
        for (int ni = 0; ni < 16; ni++) {
            float p = __expf((sacc[ni][r] - m) * SCALE_ATTN);
            sacc[ni][r] = p;
            s += p;
        }
#pragma unroll
        for (int off = 1; off < 16; off <<= 1) s += __shfl_xor(s, off, 64);
        float inv = 1.0f / s;
#pragma unroll
        for (int ni = 0; ni < 16; ni++) sacc[ni][r] *= inv;
    }
    __syncthreads();  // all waves done reading Ks before Ps overwrites it

    bf16_t* Ps = SM;  // alias over Ks
#pragma unroll
    for (int r = 0; r < 4; r++) {
        int row = w * 16 + quad * 4 + r;
#pragma unroll
        for (int ni = 0; ni < 16; ni++) {
            int col = ni * 16 + l16;
            Ps[row * 256 + (((col >> 3) ^ (row & 7)) * 8) + (col & 7)] =
                f2b(sacc[ni][r]);
        }
    }
    __syncthreads();

    // PV: O[64 q][64 d]; wave w rows [w*16, w*16+16)
    f32x4 oacc[4] = {};
#pragma unroll
    for (int s = 0; s < 8; s++) {
        int prow = w * 16 + l16;
        bf16x8 ap = *(const bf16x8*)&Ps[prow * 256 + (((s * 4 + quad) ^ (prow & 7)) * 8)];
#pragma unroll
        for (int ni = 0; ni < 4; ni++) {
            int vr = ni * 16 + l16;
            bf16x8 bv = *(const bf16x8*)&Vt[vr * 256 + (((s * 4 + quad) ^ (vr & 7)) * 8)];
            oacc[ni] = MFMA16(ap, bv, oacc[ni]);
        }
    }
#pragma unroll
    for (int r = 0; r < 4; r++) {
        long orow = (long)(b * TX + qt * 64 + w * 16 + quad * 4 + r) * LATENT + h * HD;
#pragma unroll
        for (int ni = 0; ni < 4; ni++)
            Ob[orow + ni * 16 + l16] = f2b(oacc[ni][r]);
    }
}

// ------- LayerNorm: bf16 in, f32 gamma/beta (raw inputs), bf16 out -------
__global__ __launch_bounds__(256) void ln_k(const bf16_t* __restrict__ O,
                                            const float* __restrict__ g,
                                            const float* __restrict__ bb,
                                            bf16_t* __restrict__ H) {
    long row = blockIdx.x;
    int c = threadIdx.x * 4;
    bf16x4 v = *(const bf16x4*)(O + row * LATENT + c);
    float vv[4] = {b2f(v[0]), b2f(v[1]), b2f(v[2]), b2f(v[3])};
    float s = vv[0] + vv[1] + vv[2] + vv[3];
    float s2 = vv[0] * vv[0] + vv[1] * vv[1] + vv[2] * vv[2] + vv[3] * vv[3];
#pragma unroll
    for (int off = 1; off < 64; off <<= 1) {
        s += __shfl_xor(s, off, 64);
        s2 += __shfl_xor(s2, off, 64);
    }
    __shared__ float red[8];
    int lane = threadIdx.x & 63, w = threadIdx.x >> 6;
    if (lane == 0) { red[w] = s; red[w + 4] = s2; }
    __syncthreads();
    s = red[0] + red[1] + red[2] + red[3];
    s2 = red[4] + red[5] + red[6] + red[7];
    float mu = s * (1.0f / 1024.0f);
    float var = s2 * (1.0f / 1024.0f) - mu * mu;
    float rstd = rsqrtf(var + 1e-5f);
    bf16_t* out = H + row * LATENT + c;
#pragma unroll
    for (int j = 0; j < 4; j++)
        out[j] = f2b((vv[j] - mu) * rstd * g[c + j] + bb[c + j]);
}

// ---------------- launch ----------------
extern "C" void kernel_launch(void* const* d_in, const int* in_sizes, int n_in,
                              void* d_out, int out_size, void* d_ws,
                              size_t ws_size, hipStream_t stream) {
    // Inputs are FLOAT32; output buffer is FLOAT32 (reference output dtype).
    const float* x = (const float*)d_in[0];
    const float* xf = (const float*)d_in[1];
    const float* Wq = (const float*)d_in[2];
    const float* bq = (const float*)d_in[3];
    const float* Wk = (const float*)d_in[4];
    const float* bk = (const float*)d_in[5];
    const float* Wv = (const float*)d_in[6];
    const float* bv = (const float*)d_in[7];
    const float* Wo = (const float*)d_in[8];
    const float* bo = (const float*)d_in[9];
    const float* lng = (const float*)d_in[10];
    const float* lnb = (const float*)d_in[11];
    const float* W1 = (const float*)d_in[12];
    const float* b1 = (const float*)d_in[13];
    const float* W2 = (const float*)d_in[14];
    const float* b2 = (const float*)d_in[15];

    char* ws = (char*)d_ws;
    size_t off = 0;
    auto alloc = [&](size_t bytes) {
        void* p = ws + off;
        off += (bytes + 255) & ~(size_t)255;
        return p;
    };
    // persistent region (~87 MB)
    bf16_t* WqT = (bf16_t*)alloc((size_t)1024 * 1024 * 2);
    bf16_t* WkT = (bf16_t*)alloc((size_t)1024 * 768 * 2);
    bf16_t* WvT = (bf16_t*)alloc((size_t)1024 * 768 * 2);
    bf16_t* WoT = (bf16_t*)alloc((size_t)1024 * 1024 * 2);
    bf16_t* W1T = (bf16_t*)alloc((size_t)4096 * 1024 * 2);
    bf16_t* W2T = (bf16_t*)alloc((size_t)1024 * 4096 * 2);
    bf16_t* Obuf = (bf16_t*)alloc((size_t)16384 * 1024 * 2);  // attn proj out
    bf16_t* Hbuf = (bf16_t*)alloc((size_t)16384 * 1024 * 2);  // LN out
    // transient region (dead before FFN) — H1 aliases it
    size_t transient0 = off;
    bf16_t* xc = (bf16_t*)alloc((size_t)16384 * 1024 * 2);
    bf16_t* xfc = (bf16_t*)alloc((size_t)1024 * 768 * 2);
    bf16_t* Qbuf = (bf16_t*)alloc((size_t)16384 * 1024 * 2);
    bf16_t* Kbuf = (bf16_t*)alloc((size_t)1024 * 1024 * 2);
    bf16_t* Vbuf = (bf16_t*)alloc((size_t)1024 * 1024 * 2);
    bf16_t* Abuf = (bf16_t*)alloc((size_t)16384 * 1024 * 2);
    bf16_t* H1 = (bf16_t*)(ws + transient0);  // 128 MB over dead transients

    dim3 blk(256);
    // input converts f32 -> bf16
    cvt_k<<<dim3(4096), blk, 0, stream>>>(x, xc, (long)16384 * 1024 / 4);
    cvt_k<<<dim3(768), blk, 0, stream>>>(xf, xfc, (long)1024 * 768 / 4);
    // all weight transposes (+convert) in one launch
    tr6_k<<<dim3(11776), blk, 0, stream>>>(Wq, WqT, Wk, WkT, Wv, WvT,
                                           Wo, WoT, W1, W1T, W2, W2T);

    // projections
    gemm_k<0><<<dim3(128, 8), blk, 0, stream>>>(xc, WqT, bq, Qbuf, nullptr, nullptr, 16384, 1024, 1024);
    gemm_k<0><<<dim3(8, 8), blk, 0, stream>>>(xfc, WkT, bk, Kbuf, nullptr, nullptr, 1024, 1024, 768);
    gemm_k<0><<<dim3(8, 8), blk, 0, stream>>>(xfc, WvT, bv, Vbuf, nullptr, nullptr, 1024, 1024, 768);
    // attention
    attn_k<<<dim3(4096), blk, 0, stream>>>(Qbuf, Kbuf, Vbuf, Abuf);
    // output projection
    gemm_k<0><<<dim3(128, 8), blk, 0, stream>>>(Abuf, WoT, bo, Obuf, nullptr, nullptr, 16384, 1024, 1024);
    // layernorm
    ln_k<<<dim3(16384), blk, 0, stream>>>(Obuf, lng, lnb, Hbuf);
    // FFN
    gemm_k<2><<<dim3(128, 32), blk, 0, stream>>>(Hbuf, W1T, b1, H1, nullptr, nullptr, 16384, 4096, 1024);
    gemm_k<3><<<dim3(128, 8), blk, 0, stream>>>(H1, W2T, b2, d_out, Obuf, x, 16384, 1024, 4096);
}

// Round 6
// 709.309 us; speedup vs baseline: 3.2816x; 1.0331x over previous
//
#include <hip/hip_runtime.h>
#include <hip/hip_bf16.h>
#include <cmath>

typedef __bf16 bf16_t;
typedef __bf16 bf16x8 __attribute__((ext_vector_type(8)));
typedef __bf16 bf16x4 __attribute__((ext_vector_type(4)));
typedef float f32x4 __attribute__((ext_vector_type(4)));
typedef float f32x16 __attribute__((ext_vector_type(16)));

#define LATENT 1024
#define HEADS 16
#define HD 64
#define TX 4096
#define TXF 256
#define SCALE_ATTN 0.125f

static __device__ __forceinline__ float b2f(bf16_t b) { return (float)b; }
static __device__ __forceinline__ bf16_t f2b(float f) { return (bf16_t)f; }

// async global->LDS, 16B per lane; LDS dest = wave-uniform base + lane*16
static __device__ __forceinline__ void glds16(const bf16_t* g, bf16_t* l) {
    __builtin_amdgcn_global_load_lds(
        (const __attribute__((address_space(1))) void*)g,
        (__attribute__((address_space(3))) void*)l, 16, 0, 0);
}

#define MFMA16(a, b, c) __builtin_amdgcn_mfma_f32_16x16x32_bf16(a, b, c, 0, 0, 0)
#define MFMA32(a, b, c) __builtin_amdgcn_mfma_f32_32x32x16_bf16(a, b, c, 0, 0, 0)

// ---------------- f32 -> bf16 convert (vectorized, grid-stride) ----------
__global__ __launch_bounds__(256) void cvt_k(const float* __restrict__ in,
                                             bf16_t* __restrict__ out, long n4) {
    long i = (long)blockIdx.x * 256 + threadIdx.x;
    long stride = (long)gridDim.x * 256;
    for (; i < n4; i += stride) {
        float4 v = ((const float4*)in)[i];
        bf16x4 o;
        o[0] = f2b(v.x); o[1] = f2b(v.y); o[2] = f2b(v.z); o[3] = f2b(v.w);
        *(bf16x4*)&out[i * 4] = o;
    }
}

// ------ merged transpose+convert for all 6 weights: f32 [R][C] -> bf16 [C][R]
__global__ __launch_bounds__(256) void tr6_k(
    const float* __restrict__ s0, bf16_t* __restrict__ d0,
    const float* __restrict__ s1, bf16_t* __restrict__ d1,
    const float* __restrict__ s2, bf16_t* __restrict__ d2,
    const float* __restrict__ s3, bf16_t* __restrict__ d3,
    const float* __restrict__ s4, bf16_t* __restrict__ d4,
    const float* __restrict__ s5, bf16_t* __restrict__ d5) {
    int id = blockIdx.x;
    const float* src; bf16_t* dst; int R, C, bx, by;
    if (id < 1024)      { src = s0; dst = d0; R = 1024; C = 1024; bx = id & 31;  by = id >> 5; }
    else if (id < 1792) { id -= 1024; src = s1; dst = d1; R = 768;  C = 1024; bx = id & 31;  by = id >> 5; }
    else if (id < 2560) { id -= 1792; src = s2; dst = d2; R = 768;  C = 1024; bx = id & 31;  by = id >> 5; }
    else if (id < 3584) { id -= 2560; src = s3; dst = d3; R = 1024; C = 1024; bx = id & 31;  by = id >> 5; }
    else if (id < 7680) { id -= 3584; src = s4; dst = d4; R = 1024; C = 4096; bx = id & 127; by = id >> 7; }
    else                { id -= 7680; src = s5; dst = d5; R = 4096; C = 1024; bx = id & 31;  by = id >> 5; }
    __shared__ float t[32][33];
    int x = threadIdx.x & 31, y0 = threadIdx.x >> 5;  // 32 x 8
    for (int i = 0; i < 32; i += 8)
        t[y0 + i][x] = src[(long)(by * 32 + y0 + i) * C + bx * 32 + x];
    __syncthreads();
    for (int i = 0; i < 32; i += 8)
        dst[(long)(bx * 32 + y0 + i) * R + by * 32 + x] = f2b(t[x][y0 + i]);
}

// ---------------- GEMM: C[M,N] = A[M,K] @ Bt[N,K]^T + bias(f32) ----------
// 128x128 tile, BK=64, m97 2-sync structure; inner math on 32x32x16 MFMA
// (same staging/swizzle; 16 ds_read + 16 MFMA per K-tile vs 16+32 before).
// A/B frag: m(n)=lane&31, k=(lane>>5)*8+j. C/D: col=lane&31,
// row=(reg&3)+8*(reg>>2)+4*(lane>>5) (HW-verified m74/m101).
// EPI: 0 = bf16 store, 2 = exact-GELU -> bf16, 3 = + resb16 + resf32 -> f32.
template <int EPI>
__global__ __launch_bounds__(256, 2) void gemm_k(
    const bf16_t* __restrict__ A, const bf16_t* __restrict__ Bt,
    const float* __restrict__ bias, void* __restrict__ C,
    const bf16_t* __restrict__ resb16, const float* __restrict__ resf32,
    int M, int N, int K) {
    __shared__ __align__(16) bf16_t As[128 * 64];
    __shared__ __align__(16) bf16_t Bs[128 * 64];
    int tid = threadIdx.x;
    int lane = tid & 63, wid = tid >> 6;
    int l32 = lane & 31, hi = lane >> 5;
    int wm = wid >> 1, wn = wid & 1;
    int srow0 = wid * 8 + (lane >> 3);
    int schunk = (lane & 7) ^ (lane >> 3);

    f32x16 acc[2][2] = {};
    long bm = blockIdx.x, bn = blockIdx.y;
    const bf16_t* Ab = A + (bm * 128 + srow0) * (long)K + schunk * 8;
    const bf16_t* Bb = Bt + (bn * 128 + srow0) * (long)K + schunk * 8;
    bf16_t* AsD = As + wid * 512;  // +t*2048; HW adds lane*16B (=lane*8 elems)
    bf16_t* BsD = Bs + wid * 512;

    int ra0 = wm * 64 + l32, ra1 = wm * 64 + 32 + l32;
    int rb0 = wn * 64 + l32, rb1 = wn * 64 + 32 + l32;

    for (int k0 = 0; k0 < K; k0 += 64) {
        __syncthreads();  // previous compute done reading LDS
#pragma unroll
        for (int t = 0; t < 4; t++) {
            glds16(Ab + k0 + (long)t * 32 * K, AsD + t * 2048);
            glds16(Bb + k0 + (long)t * 32 * K, BsD + t * 2048);
        }
        __syncthreads();  // drains vmcnt -> LDS ready
#pragma unroll
        for (int kp = 0; kp < 2; kp++) {
            bf16x8 af[2][2], bfr[2][2];
#pragma unroll
            for (int ks = 0; ks < 2; ks++) {
                int ch = (kp * 2 + ks) * 2 + hi;  // chunk 0..7 over K=64
                af[0][ks] = *(const bf16x8*)&As[ra0 * 64 + ((ch ^ (ra0 & 7)) * 8)];
                af[1][ks] = *(const bf16x8*)&As[ra1 * 64 + ((ch ^ (ra1 & 7)) * 8)];
                bfr[0][ks] = *(const bf16x8*)&Bs[rb0 * 64 + ((ch ^ (rb0 & 7)) * 8)];
                bfr[1][ks] = *(const bf16x8*)&Bs[rb1 * 64 + ((ch ^ (rb1 & 7)) * 8)];
            }
#pragma unroll
            for (int ks = 0; ks < 2; ks++)
#pragma unroll
                for (int mi = 0; mi < 2; mi++)
#pragma unroll
                    for (int ni = 0; ni < 2; ni++)
                        acc[mi][ni] = MFMA32(af[mi][ks], bfr[ni][ks], acc[mi][ni]);
        }
    }

    int colb = (int)bn * 128 + wn * 64;
    float bvv[2];
    bvv[0] = bias[colb + l32];
    bvv[1] = bias[colb + 32 + l32];
#pragma unroll
    for (int mi = 0; mi < 2; mi++) {
#pragma unroll
        for (int reg = 0; reg < 16; reg++) {
            long grow = bm * 128 + wm * 64 + mi * 32 +
                        (reg & 3) + 8 * (reg >> 2) + 4 * hi;
            long ro = grow * (long)N;
#pragma unroll
            for (int ni = 0; ni < 2; ni++) {
                long idx = ro + colb + ni * 32 + l32;
                float v = acc[mi][ni][reg] + bvv[ni];
                if (EPI == 0) {
                    ((bf16_t*)C)[idx] = f2b(v);
                } else if (EPI == 2) {
                    ((bf16_t*)C)[idx] =
                        f2b(0.5f * v * (1.0f + erff(v * 0.70710678118f)));
                } else {
                    // final: ffn + attn_out(bf16) + x(f32), stored f32
                    ((float*)C)[idx] = v + b2f(resb16[idx]) + resf32[idx];
                }
            }
        }
    }
}

// ---------------- fused attention (all-bf16 internal buffers) ------------
// Q[16384,1024], K/V[1024,1024] laid out (b*T + t, h*64 + d).
// Block: 64 q-rows of one (b,h). LDS 64KB: Ks swizzled [256][64] (later
// aliased by Ps [64][256]); Vt transposed swizzled [64 d][256 kk].
__global__ __launch_bounds__(256, 2) void attn_k(const bf16_t* __restrict__ Q,
                                                 const bf16_t* __restrict__ Kb,
                                                 const bf16_t* __restrict__ Vb,
                                                 bf16_t* __restrict__ Ob) {
    __shared__ __align__(16) bf16_t SM[32768];
    bf16_t* Ks = SM;
    bf16_t* Vt = SM + 16384;
    int tid = threadIdx.x;
    int lane = tid & 63, w = tid >> 6;
    int quad = lane >> 4, l16 = lane & 15;
    int qt = blockIdx.x & 63;
    int bh = blockIdx.x >> 6;
    int b = bh >> 4, h = bh & 15;

    {  // stage K (natural, swizzled) + V (transposed, swizzled); row = tid
        const uint4* ks = (const uint4*)(Kb + ((long)(b * TXF + tid) * LATENT + h * HD));
#pragma unroll
        for (int cc = 0; cc < 8; cc++)
            *(uint4*)&Ks[tid * 64 + ((cc ^ (tid & 7)) * 8)] = ks[cc];
        const uint4* vs = (const uint4*)(Vb + ((long)(b * TXF + tid) * LATENT + h * HD));
#pragma unroll
        for (int cc = 0; cc < 8; cc++) {
            uint4 v = vs[cc];
            const bf16_t* e = (const bf16_t*)&v;
#pragma unroll
            for (int j = 0; j < 8; j++) {
                int d = cc * 8 + j;
                Vt[d * 256 + (((tid >> 3) ^ (d & 7)) * 8) + (tid & 7)] = e[j];
            }
        }
    }
    // Q A-fragments from global (read-once): A[m=lane&15][k=quad*8+j]
    long qrow = (long)(b * TX + qt * 64 + w * 16 + l16) * LATENT + h * HD;
    bf16x8 aq0 = *(const bf16x8*)(Q + qrow + quad * 8);
    bf16x8 aq1 = *(const bf16x8*)(Q + qrow + 32 + quad * 8);
    __syncthreads();

    // scores: wave w owns q-rows [w*16, w*16+16), all 256 cols
    f32x4 sacc[16] = {};
#pragma unroll
    for (int ni = 0; ni < 16; ni++) {
        int kr = ni * 16 + l16;
        bf16x8 b0 = *(const bf16x8*)&Ks[kr * 64 + ((quad ^ (kr & 7)) * 8)];
        bf16x8 b1 = *(const bf16x8*)&Ks[kr * 64 + (((4 + quad) ^ (kr & 7)) * 8)];
        sacc[ni] = MFMA16(aq0, b0, sacc[ni]);
        sacc[ni] = MFMA16(aq1, b1, sacc[ni]);
    }
    // softmax per row (row = quad*4 + r); 16-lane butterfly stays in quad
#pragma unroll
    for (int r = 0; r < 4; r++) {
        float m = -3e38f;
#pragma unroll
        for (int ni = 0; ni < 16; ni++) m = fmaxf(m, sacc[ni][r]);
#pragma unroll
        for (int off = 1; off < 16; off <<= 1) m = fmaxf(m, __shfl_xor(m, off, 64));
        float s = 0.f;
#pragma unroll
        for (int ni = 0; ni < 16; ni++) {
            float p = __expf((sacc[ni][r] - m) * SCALE_ATTN);
            sacc[ni][r] = p;
            s += p;
        }
#pragma unroll
        for (int off = 1; off < 16; off <<= 1) s += __shfl_xor(s, off, 64);
        float inv = 1.0f / s;
#pragma unroll
        for (int ni = 0; ni < 16; ni++) sacc[ni][r] *= inv;
    }
    __syncthreads();  // all waves done reading Ks before Ps overwrites it

    bf16_t* Ps = SM;  // alias over Ks
#pragma unroll
    for (int r = 0; r < 4; r++) {
        int row = w * 16 + quad * 4 + r;
#pragma unroll
        for (int ni = 0; ni < 16; ni++) {
            int col = ni * 16 + l16;
            Ps[row * 256 + (((col >> 3) ^ (row & 7)) * 8) + (col & 7)] =
                f2b(sacc[ni][r]);
        }
    }
    __syncthreads();

    // PV: O[64 q][64 d]; wave w rows [w*16, w*16+16)
    f32x4 oacc[4] = {};
#pragma unroll
    for (int s = 0; s < 8; s++) {
        int prow = w * 16 + l16;
        bf16x8 ap = *(const bf16x8*)&Ps[prow * 256 + (((s * 4 + quad) ^ (prow & 7)) * 8)];
#pragma unroll
        for (int ni = 0; ni < 4; ni++) {
            int vr = ni * 16 + l16;
            bf16x8 bv = *(const bf16x8*)&Vt[vr * 256 + (((s * 4 + quad) ^ (vr & 7)) * 8)];
            oacc[ni] = MFMA16(ap, bv, oacc[ni]);
        }
    }
#pragma unroll
    for (int r = 0; r < 4; r++) {
        long orow = (long)(b * TX + qt * 64 + w * 16 + quad * 4 + r) * LATENT + h * HD;
#pragma unroll
        for (int ni = 0; ni < 4; ni++)
            Ob[orow + ni * 16 + l16] = f2b(oacc[ni][r]);
    }
}

// ------- LayerNorm: bf16 in, f32 gamma/beta (raw inputs), bf16 out -------
__global__ __launch_bounds__(256) void ln_k(const bf16_t* __restrict__ O,
                                            const float* __restrict__ g,
                                            const float* __restrict__ bb,
                                            bf16_t* __restrict__ H) {
    long row = blockIdx.x;
    int c = threadIdx.x * 4;
    bf16x4 v = *(const bf16x4*)(O + row * LATENT + c);
    float vv[4] = {b2f(v[0]), b2f(v[1]), b2f(v[2]), b2f(v[3])};
    float s = vv[0] + vv[1] + vv[2] + vv[3];
    float s2 = vv[0] * vv[0] + vv[1] * vv[1] + vv[2] * vv[2] + vv[3] * vv[3];
#pragma unroll
    for (int off = 1; off < 64; off <<= 1) {
        s += __shfl_xor(s, off, 64);
        s2 += __shfl_xor(s2, off, 64);
    }
    __shared__ float red[8];
    int lane = threadIdx.x & 63, w = threadIdx.x >> 6;
    if (lane == 0) { red[w] = s; red[w + 4] = s2; }
    __syncthreads();
    s = red[0] + red[1] + red[2] + red[3];
    s2 = red[4] + red[5] + red[6] + red[7];
    float mu = s * (1.0f / 1024.0f);
    float var = s2 * (1.0f / 1024.0f) - mu * mu;
    float rstd = rsqrtf(var + 1e-5f);
    bf16_t* out = H + row * LATENT + c;
#pragma unroll
    for (int j = 0; j < 4; j++)
        out[j] = f2b((vv[j] - mu) * rstd * g[c + j] + bb[c + j]);
}

// ---------------- launch ----------------
extern "C" void kernel_launch(void* const* d_in, const int* in_sizes, int n_in,
                              void* d_out, int out_size, void* d_ws,
                              size_t ws_size, hipStream_t stream) {
    // Inputs are FLOAT32; output buffer is FLOAT32 (reference output dtype).
    const float* x = (const float*)d_in[0];
    const float* xf = (const float*)d_in[1];
    const float* Wq = (const float*)d_in[2];
    const float* bq = (const float*)d_in[3];
    const float* Wk = (const float*)d_in[4];
    const float* bk = (const float*)d_in[5];
    const float* Wv = (const float*)d_in[6];
    const float* bv = (const float*)d_in[7];
    const float* Wo = (const float*)d_in[8];
    const float* bo = (const float*)d_in[9];
    const float* lng = (const float*)d_in[10];
    const float* lnb = (const float*)d_in[11];
    const float* W1 = (const float*)d_in[12];
    const float* b1 = (const float*)d_in[13];
    const float* W2 = (const float*)d_in[14];
    const float* b2 = (const float*)d_in[15];

    char* ws = (char*)d_ws;
    size_t off = 0;
    auto alloc = [&](size_t bytes) {
        void* p = ws + off;
        off += (bytes + 255) & ~(size_t)255;
        return p;
    };
    // persistent region (~87 MB)
    bf16_t* WqT = (bf16_t*)alloc((size_t)1024 * 1024 * 2);
    bf16_t* WkT = (bf16_t*)alloc((size_t)1024 * 768 * 2);
    bf16_t* WvT = (bf16_t*)alloc((size_t)1024 * 768 * 2);
    bf16_t* WoT = (bf16_t*)alloc((size_t)1024 * 1024 * 2);
    bf16_t* W1T = (bf16_t*)alloc((size_t)4096 * 1024 * 2);
    bf16_t* W2T = (bf16_t*)alloc((size_t)1024 * 4096 * 2);
    bf16_t* Obuf = (bf16_t*)alloc((size_t)16384 * 1024 * 2);  // attn proj out
    bf16_t* Hbuf = (bf16_t*)alloc((size_t)16384 * 1024 * 2);  // LN out
    // transient region (dead before FFN) — H1 aliases it
    size_t transient0 = off;
    bf16_t* xc = (bf16_t*)alloc((size_t)16384 * 1024 * 2);
    bf16_t* xfc = (bf16_t*)alloc((size_t)1024 * 768 * 2);
    bf16_t* Qbuf = (bf16_t*)alloc((size_t)16384 * 1024 * 2);
    bf16_t* Kbuf = (bf16_t*)alloc((size_t)1024 * 1024 * 2);
    bf16_t* Vbuf = (bf16_t*)alloc((size_t)1024 * 1024 * 2);
    bf16_t* Abuf = (bf16_t*)alloc((size_t)16384 * 1024 * 2);
    bf16_t* H1 = (bf16_t*)(ws + transient0);  // 128 MB over dead transients

    dim3 blk(256);
    // input converts f32 -> bf16
    cvt_k<<<dim3(4096), blk, 0, stream>>>(x, xc, (long)16384 * 1024 / 4);
    cvt_k<<<dim3(768), blk, 0, stream>>>(xf, xfc, (long)1024 * 768 / 4);
    // all weight transposes (+convert) in one launch
    tr6_k<<<dim3(11776), blk, 0, stream>>>(Wq, WqT, Wk, WkT, Wv, WvT,
                                           Wo, WoT, W1, W1T, W2, W2T);

    // projections
    gemm_k<0><<<dim3(128, 8), blk, 0, stream>>>(xc, WqT, bq, Qbuf, nullptr, nullptr, 16384, 1024, 1024);
    gemm_k<0><<<dim3(8, 8), blk, 0, stream>>>(xfc, WkT, bk, Kbuf, nullptr, nullptr, 1024, 1024, 768);
    gemm_k<0><<<dim3(8, 8), blk, 0, stream>>>(xfc, WvT, bv, Vbuf, nullptr, nullptr, 1024, 1024, 768);
    // attention
    attn_k<<<dim3(4096), blk, 0, stream>>>(Qbuf, Kbuf, Vbuf, Abuf);
    // output projection
    gemm_k<0><<<dim3(128, 8), blk, 0, stream>>>(Abuf, WoT, bo, Obuf, nullptr, nullptr, 16384, 1024, 1024);
    // layernorm
    ln_k<<<dim3(16384), blk, 0, stream>>>(Obuf, lng, lnb, Hbuf);
    // FFN
    gemm_k<2><<<dim3(128, 32), blk, 0, stream>>>(Hbuf, W1T, b1, H1, nullptr, nullptr, 16384, 4096, 1024);
    gemm_k<3><<<dim3(128, 8), blk, 0, stream>>>(H1, W2T, b2, d_out, Obuf, x, 16384, 1024, 4096);
}

// Round 7
// 634.929 us; speedup vs baseline: 3.6661x; 1.1171x over previous
//
#include <hip/hip_runtime.h>
#include <hip/hip_bf16.h>
#include <cmath>

typedef __bf16 bf16_t;
typedef __bf16 bf16x8 __attribute__((ext_vector_type(8)));
typedef __bf16 bf16x4 __attribute__((ext_vector_type(4)));
typedef float f32x4 __attribute__((ext_vector_type(4)));

#define LATENT 1024
#define HEADS 16
#define HD 64
#define TX 4096
#define TXF 256
#define SCALE_ATTN 0.125f

static __device__ __forceinline__ float b2f(bf16_t b) { return (float)b; }
static __device__ __forceinline__ bf16_t f2b(float f) { return (bf16_t)f; }

// async global->LDS, 16B per lane; LDS dest = wave-uniform base + lane*16
static __device__ __forceinline__ void glds16(const bf16_t* g, bf16_t* l) {
    __builtin_amdgcn_global_load_lds(
        (const __attribute__((address_space(1))) void*)g,
        (__attribute__((address_space(3))) void*)l, 16, 0, 0);
}

#define MFMA16(a, b, c) __builtin_amdgcn_mfma_f32_16x16x32_bf16(a, b, c, 0, 0, 0)

// ---- merged prep: cvt x, cvt xf, transpose+convert all 6 weights --------
// segments by blockIdx.x: [0,4096) cvt x | [4096,4864) cvt xf |
// [4864,16640) = 11776 transpose tiles (same table as tr6).
__global__ __launch_bounds__(256) void prep_k(
    const float* __restrict__ x, bf16_t* __restrict__ xc,
    const float* __restrict__ xf, bf16_t* __restrict__ xfc,
    const float* __restrict__ s0, bf16_t* __restrict__ d0,
    const float* __restrict__ s1, bf16_t* __restrict__ d1,
    const float* __restrict__ s2, bf16_t* __restrict__ d2,
    const float* __restrict__ s3, bf16_t* __restrict__ d3,
    const float* __restrict__ s4, bf16_t* __restrict__ d4,
    const float* __restrict__ s5, bf16_t* __restrict__ d5) {
    __shared__ float t[32][33];
    int id = blockIdx.x;
    if (id < 4864) {  // f32 -> bf16 convert, vectorized
        const float* in; bf16_t* out; long n4, i, stride;
        if (id < 4096) {
            in = x; out = xc; n4 = (long)16384 * 1024 / 4;
            i = (long)id * 256 + threadIdx.x; stride = (long)4096 * 256;
        } else {
            in = xf; out = xfc; n4 = (long)1024 * 768 / 4;
            i = (long)(id - 4096) * 256 + threadIdx.x; stride = (long)768 * 256;
        }
        for (; i < n4; i += stride) {
            float4 v = ((const float4*)in)[i];
            bf16x4 o;
            o[0] = f2b(v.x); o[1] = f2b(v.y); o[2] = f2b(v.z); o[3] = f2b(v.w);
            *(bf16x4*)&out[i * 4] = o;
        }
        return;
    }
    id -= 4864;
    const float* src; bf16_t* dst; int R, C, bx, by;
    if (id < 1024)      { src = s0; dst = d0; R = 1024; C = 1024; bx = id & 31;  by = id >> 5; }
    else if (id < 1792) { id -= 1024; src = s1; dst = d1; R = 768;  C = 1024; bx = id & 31;  by = id >> 5; }
    else if (id < 2560) { id -= 1792; src = s2; dst = d2; R = 768;  C = 1024; bx = id & 31;  by = id >> 5; }
    else if (id < 3584) { id -= 2560; src = s3; dst = d3; R = 1024; C = 1024; bx = id & 31;  by = id >> 5; }
    else if (id < 7680) { id -= 3584; src = s4; dst = d4; R = 1024; C = 4096; bx = id & 127; by = id >> 7; }
    else                { id -= 7680; src = s5; dst = d5; R = 4096; C = 1024; bx = id & 31;  by = id >> 5; }
    int xx = threadIdx.x & 31, y0 = threadIdx.x >> 5;  // 32 x 8
    for (int i = 0; i < 32; i += 8)
        t[y0 + i][xx] = src[(long)(by * 32 + y0 + i) * C + bx * 32 + xx];
    __syncthreads();
    for (int i = 0; i < 32; i += 8)
        dst[(long)(bx * 32 + y0 + i) * R + by * 32 + xx] = f2b(t[xx][y0 + i]);
}

// ---------------- GEMM: C[M,N] = A[M,K] @ Bt[N,K]^T + bias(f32) ----------
// 128x128 tile, BK=64, m97 2-sync structure (verified: 41% MfmaUtil, 64 VGPR,
// 0 bank conflicts). EPI: 0 = bf16 store, 2 = exact-GELU -> bf16,
//      3 = + resb16(bf16) + resf32(f32) -> F32 store (final output)
template <int EPI>
__global__ __launch_bounds__(256, 2) void gemm_k(
    const bf16_t* __restrict__ A, const bf16_t* __restrict__ Bt,
    const float* __restrict__ bias, void* __restrict__ C,
    const bf16_t* __restrict__ resb16, const float* __restrict__ resf32,
    int M, int N, int K) {
    __shared__ __align__(16) bf16_t As[128 * 64];
    __shared__ __align__(16) bf16_t Bs[128 * 64];
    int tid = threadIdx.x;
    int lane = tid & 63, wid = tid >> 6;
    int quad = lane >> 4, l16 = lane & 15;
    int wm = wid >> 1, wn = wid & 1;
    int srow0 = wid * 8 + (lane >> 3);
    int schunk = (lane & 7) ^ (lane >> 3);

    f32x4 acc[4][4] = {};
    long bm = blockIdx.x, bn = blockIdx.y;
    const bf16_t* Ab = A + (bm * 128 + srow0) * (long)K + schunk * 8;
    const bf16_t* Bb = Bt + (bn * 128 + srow0) * (long)K + schunk * 8;
    bf16_t* AsD = As + wid * 512;  // +t*2048; HW adds lane*16B (=lane*8 elems)
    bf16_t* BsD = Bs + wid * 512;

    for (int k0 = 0; k0 < K; k0 += 64) {
        __syncthreads();  // previous compute done reading LDS
#pragma unroll
        for (int t = 0; t < 4; t++) {
            glds16(Ab + k0 + (long)t * 32 * K, AsD + t * 2048);
            glds16(Bb + k0 + (long)t * 32 * K, BsD + t * 2048);
        }
        __syncthreads();  // drains vmcnt -> LDS ready
#pragma unroll
        for (int s = 0; s < 2; s++) {
            bf16x8 af[4], bfr[4];
#pragma unroll
            for (int mi = 0; mi < 4; mi++) {
                int r = wm * 64 + mi * 16 + l16;
                af[mi] = *(const bf16x8*)&As[r * 64 + (((s * 4 + quad) ^ (r & 7)) * 8)];
            }
#pragma unroll
            for (int ni = 0; ni < 4; ni++) {
                int r = wn * 64 + ni * 16 + l16;
                bfr[ni] = *(const bf16x8*)&Bs[r * 64 + (((s * 4 + quad) ^ (r & 7)) * 8)];
            }
#pragma unroll
            for (int mi = 0; mi < 4; mi++)
#pragma unroll
                for (int ni = 0; ni < 4; ni++)
                    acc[mi][ni] = MFMA16(af[mi], bfr[ni], acc[mi][ni]);
        }
    }

    // C/D layout: col = lane&15, row = quad*4 + reg (verified m89/m91)
    int colb = (int)bn * 128 + wn * 64;
    float bvv[4];
#pragma unroll
    for (int ni = 0; ni < 4; ni++) bvv[ni] = bias[colb + ni * 16 + l16];
#pragma unroll
    for (int mi = 0; mi < 4; mi++) {
        long grow = bm * 128 + wm * 64 + mi * 16 + quad * 4;
#pragma unroll
        for (int r = 0; r < 4; r++) {
            long ro = (grow + r) * (long)N;
#pragma unroll
            for (int ni = 0; ni < 4; ni++) {
                long idx = ro + colb + ni * 16 + l16;
                float v = acc[mi][ni][r] + bvv[ni];
                if (EPI == 0) {
                    ((bf16_t*)C)[idx] = f2b(v);
                } else if (EPI == 2) {
                    ((bf16_t*)C)[idx] =
                        f2b(0.5f * v * (1.0f + erff(v * 0.70710678118f)));
                } else {
                    // final: ffn + attn_out(bf16) + x(f32), stored f32
                    ((float*)C)[idx] = v + b2f(resb16[idx]) + resf32[idx];
                }
            }
        }
    }
}

// ---- merged Q/K/V projection: one launch, 1152 blocks -------------------
// [0,1024): Q = xc @ WqT (128x8 tiles) | [1024,1088): K-proj (8x8) |
// [1088,1152): V-proj (8x8). Body = verbatim r0 gemm, EPI=0.
__global__ __launch_bounds__(256, 2) void gemm3_k(
    const bf16_t* __restrict__ xc, const bf16_t* __restrict__ WqT,
    const float* __restrict__ bq, bf16_t* __restrict__ Qb,
    const bf16_t* __restrict__ xfc, const bf16_t* __restrict__ WkT,
    const float* __restrict__ bk, bf16_t* __restrict__ Kb,
    const bf16_t* __restrict__ WvT, const float* __restrict__ bv,
    bf16_t* __restrict__ Vb) {
    __shared__ __align__(16) bf16_t As[128 * 64];
    __shared__ __align__(16) bf16_t Bs[128 * 64];
    int id = blockIdx.x;
    const bf16_t *A, *Bt; const float* bias; bf16_t* C; int N, K; long bm, bn;
    if (id < 1024) {
        A = xc; Bt = WqT; bias = bq; C = Qb; N = 1024; K = 1024;
        bm = id & 127; bn = id >> 7;
    } else if (id < 1088) {
        int u = id - 1024;
        A = xfc; Bt = WkT; bias = bk; C = Kb; N = 1024; K = 768;
        bm = u & 7; bn = u >> 3;
    } else {
        int u = id - 1088;
        A = xfc; Bt = WvT; bias = bv; C = Vb; N = 1024; K = 768;
        bm = u & 7; bn = u >> 3;
    }
    int tid = threadIdx.x;
    int lane = tid & 63, wid = tid >> 6;
    int quad = lane >> 4, l16 = lane & 15;
    int wm = wid >> 1, wn = wid & 1;
    int srow0 = wid * 8 + (lane >> 3);
    int schunk = (lane & 7) ^ (lane >> 3);

    f32x4 acc[4][4] = {};
    const bf16_t* Ab = A + (bm * 128 + srow0) * (long)K + schunk * 8;
    const bf16_t* Bb = Bt + (bn * 128 + srow0) * (long)K + schunk * 8;
    bf16_t* AsD = As + wid * 512;
    bf16_t* BsD = Bs + wid * 512;

    for (int k0 = 0; k0 < K; k0 += 64) {
        __syncthreads();
#pragma unroll
        for (int t = 0; t < 4; t++) {
            glds16(Ab + k0 + (long)t * 32 * K, AsD + t * 2048);
            glds16(Bb + k0 + (long)t * 32 * K, BsD + t * 2048);
        }
        __syncthreads();
#pragma unroll
        for (int s = 0; s < 2; s++) {
            bf16x8 af[4], bfr[4];
#pragma unroll
            for (int mi = 0; mi < 4; mi++) {
                int r = wm * 64 + mi * 16 + l16;
                af[mi] = *(const bf16x8*)&As[r * 64 + (((s * 4 + quad) ^ (r & 7)) * 8)];
            }
#pragma unroll
            for (int ni = 0; ni < 4; ni++) {
                int r = wn * 64 + ni * 16 + l16;
                bfr[ni] = *(const bf16x8*)&Bs[r * 64 + (((s * 4 + quad) ^ (r & 7)) * 8)];
            }
#pragma unroll
            for (int mi = 0; mi < 4; mi++)
#pragma unroll
                for (int ni = 0; ni < 4; ni++)
                    acc[mi][ni] = MFMA16(af[mi], bfr[ni], acc[mi][ni]);
        }
    }

    int colb = (int)bn * 128 + wn * 64;
    float bvv[4];
#pragma unroll
    for (int ni = 0; ni < 4; ni++) bvv[ni] = bias[colb + ni * 16 + l16];
#pragma unroll
    for (int mi = 0; mi < 4; mi++) {
        long grow = bm * 128 + wm * 64 + mi * 16 + quad * 4;
#pragma unroll
        for (int r = 0; r < 4; r++) {
            long ro = (grow + r) * (long)N;
#pragma unroll
            for (int ni = 0; ni < 4; ni++)
                C[ro + colb + ni * 16 + l16] = f2b(acc[mi][ni][r] + bvv[ni]);
        }
    }
}

// ---------------- fused attention (all-bf16 internal buffers) ------------
// Q[16384,1024], K/V[1024,1024] laid out (b*T + t, h*64 + d).
// Block: 64 q-rows of one (b,h). LDS 64KB: Ks swizzled [256][64] (later
// aliased by Ps [64][256]); Vt transposed swizzled [64 d][256 kk].
__global__ __launch_bounds__(256, 2) void attn_k(const bf16_t* __restrict__ Q,
                                                 const bf16_t* __restrict__ Kb,
                                                 const bf16_t* __restrict__ Vb,
                                                 bf16_t* __restrict__ Ob) {
    __shared__ __align__(16) bf16_t SM[32768];
    bf16_t* Ks = SM;
    bf16_t* Vt = SM + 16384;
    int tid = threadIdx.x;
    int lane = tid & 63, w = tid >> 6;
    int quad = lane >> 4, l16 = lane & 15;
    int qt = blockIdx.x & 63;
    int bh = blockIdx.x >> 6;
    int b = bh >> 4, h = bh & 15;

    {  // stage K (natural, swizzled) + V (transposed, swizzled); row = tid
        const uint4* ks = (const uint4*)(Kb + ((long)(b * TXF + tid) * LATENT + h * HD));
#pragma unroll
        for (int cc = 0; cc < 8; cc++)
            *(uint4*)&Ks[tid * 64 + ((cc ^ (tid & 7)) * 8)] = ks[cc];
        const uint4* vs = (const uint4*)(Vb + ((long)(b * TXF + tid) * LATENT + h * HD));
#pragma unroll
        for (int cc = 0; cc < 8; cc++) {
            uint4 v = vs[cc];
            const bf16_t* e = (const bf16_t*)&v;
#pragma unroll
            for (int j = 0; j < 8; j++) {
                int d = cc * 8 + j;
                Vt[d * 256 + (((tid >> 3) ^ (d & 7)) * 8) + (tid & 7)] = e[j];
            }
        }
    }
    // Q A-fragments from global (read-once): A[m=lane&15][k=quad*8+j]
    long qrow = (long)(b * TX + qt * 64 + w * 16 + l16) * LATENT + h * HD;
    bf16x8 aq0 = *(const bf16x8*)(Q + qrow + quad * 8);
    bf16x8 aq1 = *(const bf16x8*)(Q + qrow + 32 + quad * 8);
    __syncthreads();

    // scores: wave w owns q-rows [w*16, w*16+16), all 256 cols
    f32x4 sacc[16] = {};
#pragma unroll
    for (int ni = 0; ni < 16; ni++) {
        int kr = ni * 16 + l16;
        bf16x8 b0 = *(const bf16x8*)&Ks[kr * 64 + ((quad ^ (kr & 7)) * 8)];
        bf16x8 b1 = *(const bf16x8*)&Ks[kr * 64 + (((4 + quad) ^ (kr & 7)) * 8)];
        sacc[ni] = MFMA16(aq0, b0, sacc[ni]);
        sacc[ni] = MFMA16(aq1, b1, sacc[ni]);
    }
    // softmax per row (row = quad*4 + r); 16-lane butterfly stays in quad
#pragma unroll
    for (int r = 0; r < 4; r++) {
        float m = -3e38f;
#pragma unroll
        for (int ni = 0; ni < 16; ni++) m = fmaxf(m, sacc[ni][r]);
#pragma unroll
        for (int off = 1; off < 16; off <<= 1) m = fmaxf(m, __shfl_xor(m, off, 64));
        float s = 0.f;
#pragma unroll
        for (int ni = 0; ni < 16; ni++) {
            float p = __expf((sacc[ni][r] - m) * SCALE_ATTN);
            sacc[ni][r] = p;
            s += p;
        }
#pragma unroll
        for (int off = 1; off < 16; off <<= 1) s += __shfl_xor(s, off, 64);
        float inv = 1.0f / s;
#pragma unroll
        for (int ni = 0; ni < 16; ni++) sacc[ni][r] *= inv;
    }
    __syncthreads();  // all waves done reading Ks before Ps overwrites it

    bf16_t* Ps = SM;  // alias over Ks
#pragma unroll
    for (int r = 0; r < 4; r++) {
        int row = w * 16 + quad * 4 + r;
#pragma unroll
        for (int ni = 0; ni < 16; ni++) {
            int col = ni * 16 + l16;
            Ps[row * 256 + (((col >> 3) ^ (row & 7)) * 8) + (col & 7)] =
                f2b(sacc[ni][r]);
        }
    }
    __syncthreads();

    // PV: O[64 q][64 d]; wave w rows [w*16, w*16+16)
    f32x4 oacc[4] = {};
#pragma unroll
    for (int s = 0; s < 8; s++) {
        int prow = w * 16 + l16;
        bf16x8 ap = *(const bf16x8*)&Ps[prow * 256 + (((s * 4 + quad) ^ (prow & 7)) * 8)];
#pragma unroll
        for (int ni = 0; ni < 4; ni++) {
            int vr = ni * 16 + l16;
            bf16x8 bv = *(const bf16x8*)&Vt[vr * 256 + (((s * 4 + quad) ^ (vr & 7)) * 8)];
            oacc[ni] = MFMA16(ap, bv, oacc[ni]);
        }
    }
#pragma unroll
    for (int r = 0; r < 4; r++) {
        long orow = (long)(b * TX + qt * 64 + w * 16 + quad * 4 + r) * LATENT + h * HD;
#pragma unroll
        for (int ni = 0; ni < 4; ni++)
            Ob[orow + ni * 16 + l16] = f2b(oacc[ni][r]);
    }
}

// ------- LayerNorm: bf16 in, f32 gamma/beta (raw inputs), bf16 out -------
__global__ __launch_bounds__(256) void ln_k(const bf16_t* __restrict__ O,
                                            const float* __restrict__ g,
                                            const float* __restrict__ bb,
                                            bf16_t* __restrict__ H) {
    long row = blockIdx.x;
    int c = threadIdx.x * 4;
    bf16x4 v = *(const bf16x4*)(O + row * LATENT + c);
    float vv[4] = {b2f(v[0]), b2f(v[1]), b2f(v[2]), b2f(v[3])};
    float s = vv[0] + vv[1] + vv[2] + vv[3];
    float s2 = vv[0] * vv[0] + vv[1] * vv[1] + vv[2] * vv[2] + vv[3] * vv[3];
#pragma unroll
    for (int off = 1; off < 64; off <<= 1) {
        s += __shfl_xor(s, off, 64);
        s2 += __shfl_xor(s2, off, 64);
    }
    __shared__ float red[8];
    int lane = threadIdx.x & 63, w = threadIdx.x >> 6;
    if (lane == 0) { red[w] = s; red[w + 4] = s2; }
    __syncthreads();
    s = red[0] + red[1] + red[2] + red[3];
    s2 = red[4] + red[5] + red[6] + red[7];
    float mu = s * (1.0f / 1024.0f);
    float var = s2 * (1.0f / 1024.0f) - mu * mu;
    float rstd = rsqrtf(var + 1e-5f);
    bf16_t* out = H + row * LATENT + c;
#pragma unroll
    for (int j = 0; j < 4; j++)
        out[j] = f2b((vv[j] - mu) * rstd * g[c + j] + bb[c + j]);
}

// ---------------- launch ----------------
extern "C" void kernel_launch(void* const* d_in, const int* in_sizes, int n_in,
                              void* d_out, int out_size, void* d_ws,
                              size_t ws_size, hipStream_t stream) {
    // Inputs are FLOAT32; output buffer is FLOAT32 (reference output dtype).
    const float* x = (const float*)d_in[0];
    const float* xf = (const float*)d_in[1];
    const float* Wq = (const float*)d_in[2];
    const float* bq = (const float*)d_in[3];
    const float* Wk = (const float*)d_in[4];
    const float* bk = (const float*)d_in[5];
    const float* Wv = (const float*)d_in[6];
    const float* bv = (const float*)d_in[7];
    const float* Wo = (const float*)d_in[8];
    const float* bo = (const float*)d_in[9];
    const float* lng = (const float*)d_in[10];
    const float* lnb = (const float*)d_in[11];
    const float* W1 = (const float*)d_in[12];
    const float* b1 = (const float*)d_in[13];
    const float* W2 = (const float*)d_in[14];
    const float* b2 = (const float*)d_in[15];

    char* ws = (char*)d_ws;
    size_t off = 0;
    auto alloc = [&](size_t bytes) {
        void* p = ws + off;
        off += (bytes + 255) & ~(size_t)255;
        return p;
    };
    // persistent region (~87 MB)
    bf16_t* WqT = (bf16_t*)alloc((size_t)1024 * 1024 * 2);
    bf16_t* WkT = (bf16_t*)alloc((size_t)1024 * 768 * 2);
    bf16_t* WvT = (bf16_t*)alloc((size_t)1024 * 768 * 2);
    bf16_t* WoT = (bf16_t*)alloc((size_t)1024 * 1024 * 2);
    bf16_t* W1T = (bf16_t*)alloc((size_t)4096 * 1024 * 2);
    bf16_t* W2T = (bf16_t*)alloc((size_t)1024 * 4096 * 2);
    bf16_t* Obuf = (bf16_t*)alloc((size_t)16384 * 1024 * 2);  // attn proj out
    bf16_t* Hbuf = (bf16_t*)alloc((size_t)16384 * 1024 * 2);  // LN out
    // transient region (dead before FFN) — H1 aliases it
    size_t transient0 = off;
    bf16_t* xc = (bf16_t*)alloc((size_t)16384 * 1024 * 2);
    bf16_t* xfc = (bf16_t*)alloc((size_t)1024 * 768 * 2);
    bf16_t* Qbuf = (bf16_t*)alloc((size_t)16384 * 1024 * 2);
    bf16_t* Kbuf = (bf16_t*)alloc((size_t)1024 * 1024 * 2);
    bf16_t* Vbuf = (bf16_t*)alloc((size_t)1024 * 1024 * 2);
    bf16_t* Abuf = (bf16_t*)alloc((size_t)16384 * 1024 * 2);
    bf16_t* H1 = (bf16_t*)(ws + transient0);  // 128 MB over dead transients

    dim3 blk(256);
    // prep: input converts + all weight transposes in ONE launch
    prep_k<<<dim3(16640), blk, 0, stream>>>(x, xc, xf, xfc,
                                            Wq, WqT, Wk, WkT, Wv, WvT,
                                            Wo, WoT, W1, W1T, W2, W2T);
    // Q/K/V projections in ONE launch
    gemm3_k<<<dim3(1152), blk, 0, stream>>>(xc, WqT, bq, Qbuf,
                                            xfc, WkT, bk, Kbuf,
                                            WvT, bv, Vbuf);
    // attention
    attn_k<<<dim3(4096), blk, 0, stream>>>(Qbuf, Kbuf, Vbuf, Abuf);
    // output projection
    gemm_k<0><<<dim3(128, 8), blk, 0, stream>>>(Abuf, WoT, bo, Obuf, nullptr, nullptr, 16384, 1024, 1024);
    // layernorm
    ln_k<<<dim3(16384), blk, 0, stream>>>(Obuf, lng, lnb, Hbuf);
    // FFN
    gemm_k<2><<<dim3(128, 32), blk, 0, stream>>>(Hbuf, W1T, b1, H1, nullptr, nullptr, 16384, 4096, 1024);
    gemm_k<3><<<dim3(128, 8), blk, 0, stream>>>(H1, W2T, b2, d_out, Obuf, x, 16384, 1024, 4096);
}